// Round 20
// baseline (58.792 us; speedup 1.0000x reference)
//
#include <hip/hip_runtime.h>

#define B_ 4
#define T_ 4096
#define E_ 512
#define A_ 64
#define SQSCALE 0.1803368801111204f   // log2(e)/8 : folds softmax scale + exp->exp2

typedef __attribute__((ext_vector_type(8)))  short bf16x8;
typedef __attribute__((ext_vector_type(8)))  unsigned short ushort8;
typedef __attribute__((ext_vector_type(4)))  unsigned int   u32x4;
typedef __attribute__((ext_vector_type(4)))  float f32x4;
typedef __attribute__((ext_vector_type(16))) float f32x16;

__device__ __forceinline__ unsigned short f2bf(float x) {
    union { float f; unsigned int u; } v; v.f = x;
    unsigned int r = v.u + 0x7fffu + ((v.u >> 16) & 1u);
    return (unsigned short)(r >> 16);
}
__device__ __forceinline__ unsigned cvtpk(float a, float b) {
    unsigned r;
    asm("v_cvt_pk_bf16_f32 %0, %1, %2" : "=v"(r) : "v"(a), "v"(b));
    return r;
}
// v_permlane32_swap_b32 (distinct values only)
__device__ __forceinline__ void pls(unsigned &a, unsigned &b) {
    asm("v_permlane32_swap_b32 %0, %1" : "+v"(a), "+v"(b));
}

// ---- Kernel 0: W -> Wp, fragment-packed bf16 B-frags [nt 12][ks 16][lane 64]x8
__global__ __launch_bounds__(256) void prep_w(
    const float* __restrict__ Wq, const float* __restrict__ Wk,
    const float* __restrict__ Wv, unsigned short* __restrict__ Wp)
{
    const int e = blockIdx.x * 256 + threadIdx.x;   // 48*256 = 12288 entries
    const int nt = e >> 10;
    const int ks = (e >> 6) & 15;
    const int l  = e & 63;
    const int col = nt * 16 + (l & 15);
    const int kb  = ks * 32 + (l >> 4) * 8;
    const float* W = (col < 64) ? Wq : ((col < 128) ? Wk : Wv);
    const int cc = col & 63;
    const float sc = (col < 64) ? SQSCALE : 1.f;
    union { unsigned short s[8]; ushort8 v; } u;
    #pragma unroll
    for (int j = 0; j < 8; ++j) u.s[j] = f2bf(W[(kb + j) * 64 + cc] * sc);
    *(ushort8*)&Wp[(size_t)e * 8] = u.v;
}

// ---- Kernel 1: QKV projection via bf16 MFMA (R17 version, byte-identical) --
__global__ __launch_bounds__(768, 4) void qkv_proj_kernel(
    const float* __restrict__ emb, const unsigned short* __restrict__ Wp,
    unsigned short* __restrict__ Qp, unsigned short* __restrict__ Kp,
    unsigned short* __restrict__ Vp)
{
    __shared__ unsigned short at[32][536];   // 33.5 KB
    __shared__ unsigned short qt[32][72];    // 4.6 KB  [q][dim]
    __shared__ unsigned short kt[32][72];    // 4.6 KB  [key][dim]
    __shared__ unsigned short vt[64][40];    // 5.1 KB  [dim][key]
    const int tid = threadIdx.x;
    const long row0 = (long)blockIdx.x * 32;

    if (tid < 512) {
        const int r = tid >> 4, c16 = tid & 15;
        const float* __restrict__ src = emb + (row0 + r) * 512;
        #pragma unroll
        for (int j = 0; j < 4; ++j) {
            const int col = j * 128 + c16 * 8;
            const float4 x0 = *(const float4*)(src + col);
            const float4 x1 = *(const float4*)(src + col + 4);
            u32x4 p;
            p[0] = cvtpk(x0.x, x0.y); p[1] = cvtpk(x0.z, x0.w);
            p[2] = cvtpk(x1.x, x1.y); p[3] = cvtpk(x1.z, x1.w);
            *(u32x4*)&at[r][col] = p;
        }
    }
    __syncthreads();

    const int w = tid >> 6, lane = tid & 63;   // w = nt tile index, 0..11
    const int c = lane & 15, hi = lane >> 4;

    f32x4 acc[2];
    acc[0] = (f32x4){0.f, 0.f, 0.f, 0.f};
    acc[1] = (f32x4){0.f, 0.f, 0.f, 0.f};

    #pragma unroll
    for (int ks = 0; ks < 16; ++ks) {
        const bf16x8 bf_ = *(const bf16x8*)&Wp[((size_t)(w * 16 + ks) * 64 + lane) * 8];
        const bf16x8 a0 = *(const bf16x8*)&at[c][ks * 32 + hi * 8];
        const bf16x8 a1 = *(const bf16x8*)&at[16 + c][ks * 32 + hi * 8];
        acc[0] = __builtin_amdgcn_mfma_f32_16x16x32_bf16(a0, bf_, acc[0], 0, 0, 0);
        acc[1] = __builtin_amdgcn_mfma_f32_16x16x32_bf16(a1, bf_, acc[1], 0, 0, 0);
    }

    #pragma unroll
    for (int rr = 0; rr < 2; ++rr)
        #pragma unroll
        for (int r4 = 0; r4 < 4; ++r4) {
            const int rloc = rr * 16 + hi * 4 + r4;
            const unsigned short v = f2bf(acc[rr][r4]);
            if (w < 4)       qt[rloc][w * 16 + c] = v;
            else if (w < 8)  kt[rloc][(w - 4) * 16 + c] = v;
            else             vt[(w - 8) * 16 + c][rloc] = v;
        }
    __syncthreads();

    const int tloc = (int)(row0 & 4095);
    const long bb = row0 >> 12;
    const int ci  = tloc >> 6;
    const int f_  = (tloc >> 5) & 1;
    const int ks0 = (tloc >> 4) & 3;      // 0 or 2
    const int tt  = tloc >> 5;            // 32-q tile index 0..127
    if (tid < 256) {
        const int kk = tid >> 6, l = tid & 63;
        const ushort8 kval = *(const ushort8*)&kt[l & 31][kk * 16 + (l >> 5) * 8];
        *(ushort8*)&Kp[((((bb * 64 + ci) * 2 + f_) * 4 + kk) * 64 + l) * 8] = kval;
        const ushort8 qval = *(const ushort8*)&qt[l & 31][kk * 16 + (l >> 5) * 8];
        *(ushort8*)&Qp[(((bb * 128 + tt) * 4 + kk) * 64 + l) * 8] = qval;
    } else if (tid < 512) {
        const int e = tid - 256;
        const int ksl = e >> 7, ct = (e >> 6) & 1, l = e & 63;
        const ushort8 val = *(const ushort8*)&vt[ct * 32 + (l & 31)][ksl * 16 + (l >> 5) * 8];
        *(ushort8*)&Vp[((((bb * 64 + ci) * 4 + ks0 + ksl) * 2 + ct) * 64 + l) * 8] = val;
    }
}

// ---- Kernel 2: causal flash attention, two-tile in-wave interleave ---------
// 256 blocks (1/CU), 8 waves, tiles {127-pp, pp} advanced TOGETHER each loop
// iteration: two independent dependence chains per wave (ILP-2).
// launch_bounds (512,1): ILP-2 needs ~240 VGPR; (512,2) forced a 128 cap ->
// 35 MB spill traffic (R19 regression). Grid is 1 block/CU anyway.
struct TS {
    const unsigned short* kptr;
    const unsigned short* vptr;
    bf16x8 qf[4];
    bf16x8 kf[2][4];
    f32x16 acc[2];
    float m, l;
    int nc, qb, ci;
};

__device__ __forceinline__ void tile_init(TS& s, int t,
    const unsigned short* __restrict__ Qpb, const unsigned short* __restrict__ Kpb,
    const unsigned short* __restrict__ Vpb, int w, int lane)
{
    s.qb = t << 5;
    s.nc = ((s.qb + 31) >> 6) + 1;
    #pragma unroll
    for (int kk = 0; kk < 4; ++kk)
        s.qf[kk] = *(const bf16x8*)&Qpb[(((size_t)t * 4 + kk) * 64 + lane) * 8];
    #pragma unroll
    for (int ct = 0; ct < 2; ++ct)
        #pragma unroll
        for (int j = 0; j < 16; ++j) s.acc[ct][j] = 0.f;
    s.m = -1e30f; s.l = 0.f;
    s.kptr = Kpb + (size_t)w * 4096 + lane * 8;
    s.vptr = Vpb + (size_t)w * 4096 + lane * 8;
    s.ci = w;
    const unsigned short* kp0 = (w < s.nc) ? s.kptr : (s.kptr - (size_t)(w - s.nc + 1) * 4096);
    #pragma unroll
    for (int f = 0; f < 2; ++f)
        #pragma unroll
        for (int kk = 0; kk < 4; ++kk)
            s.kf[f][kk] = *(const bf16x8*)&kp0[f * 2048 + kk * 512];
}

__device__ __forceinline__ void tile_step(TS& s, int h)
{
    const int s0 = s.ci << 6;

    bf16x8 vf[4][2];
    #pragma unroll
    for (int ks = 0; ks < 4; ++ks)
        #pragma unroll
        for (int ct = 0; ct < 2; ++ct)
            vf[ks][ct] = *(const bf16x8*)&s.vptr[ks * 1024 + ct * 512];

    // S^T = K Q^T : D[row=key][col=q]
    f32x16 sf[2];
    #pragma unroll
    for (int f = 0; f < 2; ++f)
        #pragma unroll
        for (int j = 0; j < 16; ++j) sf[f][j] = 0.f;
    __builtin_amdgcn_s_setprio(1);
    #pragma unroll
    for (int f = 0; f < 2; ++f)
        #pragma unroll
        for (int kk = 0; kk < 4; ++kk)
            sf[f] = __builtin_amdgcn_mfma_f32_32x32x16_bf16(s.kf[f][kk], s.qf[kk], sf[f], 0, 0, 0);
    __builtin_amdgcn_s_setprio(0);

    // prefetch next chunk's K (clamped; values unused past end)
    const unsigned short* knp = (s.ci + 8 < s.nc) ? (s.kptr + 32768) : s.kptr;
    bf16x8 kn[2][4];
    #pragma unroll
    for (int f = 0; f < 2; ++f)
        #pragma unroll
        for (int kk = 0; kk < 4; ++kk)
            kn[f][kk] = *(const bf16x8*)&knp[f * 2048 + kk * 512];

    const int c = (int)(threadIdx.x & 31);
    // causal mask: key = s0 + 32f + (r&3) + 8*(r>>2) + 4h ; q = qb + c
    if (s0 + 63 > s.qb) {
        #pragma unroll
        for (int f = 0; f < 2; ++f)
            #pragma unroll
            for (int r = 0; r < 16; ++r) {
                const int key = s0 + f * 32 + ((r & 3) + 8 * (r >> 2)) + 4 * h;
                if (key > s.qb + c) sf[f][r] = -1e30f;
            }
    }

    // ---- online softmax (exp2 domain); 4-partial tree reductions ----
    float t0 = fmaxf(sf[0][0], sf[1][0]);
    float t1 = fmaxf(sf[0][1], sf[1][1]);
    float t2 = fmaxf(sf[0][2], sf[1][2]);
    float t3 = fmaxf(sf[0][3], sf[1][3]);
    #pragma unroll
    for (int r = 4; r < 16; r += 4) {
        t0 = fmaxf(t0, fmaxf(sf[0][r],     sf[1][r]));
        t1 = fmaxf(t1, fmaxf(sf[0][r + 1], sf[1][r + 1]));
        t2 = fmaxf(t2, fmaxf(sf[0][r + 2], sf[1][r + 2]));
        t3 = fmaxf(t3, fmaxf(sf[0][r + 3], sf[1][r + 3]));
    }
    float pm = fmaxf(fmaxf(t0, t1), fmaxf(t2, t3));
    pm = fmaxf(pm, __shfl_xor(pm, 32));

    float mn = s.m;
    if (__any(pm > s.m)) {             // exact skip: if no column grew, sc == 1
        mn = fmaxf(s.m, pm);
        const float sc = exp2f(s.m - mn);   // per-lane scalar (q = c)
        s.m = mn;
        s.l *= sc;
        #pragma unroll
        for (int ct = 0; ct < 2; ++ct)
            #pragma unroll
            for (int r = 0; r < 16; ++r) s.acc[ct][r] *= sc;
    }

    float s0a = 0.f, s1a = 0.f, s2a = 0.f, s3a = 0.f;
    #pragma unroll
    for (int f = 0; f < 2; ++f)
        #pragma unroll
        for (int r = 0; r < 16; r += 4) {
            float p0 = exp2f(sf[f][r] - mn);
            float p1 = exp2f(sf[f][r + 1] - mn);
            float p2 = exp2f(sf[f][r + 2] - mn);
            float p3 = exp2f(sf[f][r + 3] - mn);
            sf[f][r] = p0; sf[f][r + 1] = p1; sf[f][r + 2] = p2; sf[f][r + 3] = p3;
            s0a += p0; s1a += p1; s2a += p2; s3a += p3;
        }
    float rs = (s0a + s1a) + (s2a + s3a);
    rs += __shfl_xor(rs, 32);
    s.l += rs;

    // ---- P -> bf16 frags via cvt_pk + permlane32_swap; O^T += V^T P ----
    #pragma unroll
    for (int f = 0; f < 2; ++f) {
        unsigned w01 = cvtpk(sf[f][0], sf[f][1]);
        unsigned w23 = cvtpk(sf[f][2], sf[f][3]);
        unsigned w45 = cvtpk(sf[f][4], sf[f][5]);
        unsigned w67 = cvtpk(sf[f][6], sf[f][7]);
        pls(w01, w45); pls(w23, w67);
        union { unsigned uu[4]; bf16x8 v; } pa0, pa1;
        pa0.uu[0] = w01; pa0.uu[1] = w23; pa0.uu[2] = w45; pa0.uu[3] = w67;
        unsigned x01 = cvtpk(sf[f][8],  sf[f][9]);
        unsigned x23 = cvtpk(sf[f][10], sf[f][11]);
        unsigned x45 = cvtpk(sf[f][12], sf[f][13]);
        unsigned x67 = cvtpk(sf[f][14], sf[f][15]);
        pls(x01, x45); pls(x23, x67);
        pa1.uu[0] = x01; pa1.uu[1] = x23; pa1.uu[2] = x45; pa1.uu[3] = x67;
        __builtin_amdgcn_s_setprio(1);
        #pragma unroll
        for (int ct = 0; ct < 2; ++ct) {
            s.acc[ct] = __builtin_amdgcn_mfma_f32_32x32x16_bf16(vf[2 * f][ct],     pa0.v, s.acc[ct], 0, 0, 0);
            s.acc[ct] = __builtin_amdgcn_mfma_f32_32x32x16_bf16(vf[2 * f + 1][ct], pa1.v, s.acc[ct], 0, 0, 0);
        }
        __builtin_amdgcn_s_setprio(0);
    }

    #pragma unroll
    for (int f = 0; f < 2; ++f)
        #pragma unroll
        for (int kk = 0; kk < 4; ++kk) s.kf[f][kk] = kn[f][kk];
    s.kptr += 32768;
    s.vptr += 32768;
    s.ci += 8;
}

__global__ __launch_bounds__(512, 1) void attn_kernel(
    const unsigned short* __restrict__ Qp, const unsigned short* __restrict__ Kp,
    const unsigned short* __restrict__ Vp, float* __restrict__ out)
{
    __shared__ float accbuf[8][32][68];   // 69.6 KB, [q][d] pad 68
    __shared__ float mbuf[8][32], lbuf[8][32];

    const int tid = threadIdx.x, w = tid >> 6, lane = tid & 63;
    const int c = lane & 31, h = lane >> 5;
    const int b = blockIdx.x & 3;
    const int pp = blockIdx.x >> 2;       // 0..63

    const unsigned short* __restrict__ Qpb = Qp + (size_t)b * 128 * 4 * 512;
    const unsigned short* __restrict__ Kpb = Kp + (size_t)b * 64 * 8 * 512;
    const unsigned short* __restrict__ Vpb = Vp + (size_t)b * 64 * 8 * 512;

    TS A, Bt;
    tile_init(A,  127 - pp, Qpb, Kpb, Vpb, w, lane);
    tile_init(Bt, pp,       Qpb, Kpb, Vpb, w, lane);
    const int itA = (A.nc  > w) ? ((A.nc  - w + 7) >> 3) : 0;
    const int itB = (Bt.nc > w) ? ((Bt.nc - w + 7) >> 3) : 0;

    for (int i = 0; i < itA; ++i) {
        tile_step(A, h);
        if (i < itB) tile_step(Bt, h);   // wave-uniform predicate; itA >= itB
    }

    // ---- merge + store, tile A then tile B (accbuf reused) ----
    #pragma unroll
    for (int which = 0; which < 2; ++which) {
        if (which == 0) {
            if (h == 0) { mbuf[w][c] = A.m; lbuf[w][c] = A.l; }
            #pragma unroll
            for (int ct = 0; ct < 2; ++ct)
                #pragma unroll
                for (int g = 0; g < 4; ++g)
                    *(float4*)&accbuf[w][c][ct * 32 + g * 8 + 4 * h] =
                        make_float4(A.acc[ct][4 * g], A.acc[ct][4 * g + 1],
                                    A.acc[ct][4 * g + 2], A.acc[ct][4 * g + 3]);
        } else {
            if (h == 0) { mbuf[w][c] = Bt.m; lbuf[w][c] = Bt.l; }
            #pragma unroll
            for (int ct = 0; ct < 2; ++ct)
                #pragma unroll
                for (int g = 0; g < 4; ++g)
                    *(float4*)&accbuf[w][c][ct * 32 + g * 8 + 4 * h] =
                        make_float4(Bt.acc[ct][4 * g], Bt.acc[ct][4 * g + 1],
                                    Bt.acc[ct][4 * g + 2], Bt.acc[ct][4 * g + 3]);
        }
        __syncthreads();
        const int qb = which ? (pp << 5) : ((127 - pp) << 5);
        #pragma unroll
        for (int i = 0; i < 4; ++i) {
            const int e = tid + i * 512;
            const int q = e >> 6, d = e & 63;
            float ms = mbuf[0][q];
            #pragma unroll
            for (int wv = 1; wv < 8; ++wv) ms = fmaxf(ms, mbuf[wv][q]);
            float ls = 0.f, os = 0.f;
            #pragma unroll
            for (int wv = 0; wv < 8; ++wv) {
                const float e_ = exp2f(mbuf[wv][q] - ms);
                ls += lbuf[wv][q] * e_;
                os += accbuf[wv][q][d] * e_;
            }
            out[((long)b * T_ + qb + q) * 64 + d] = os / ls;
        }
        __syncthreads();   // protect accbuf/mbuf/lbuf reuse
    }
}

extern "C" void kernel_launch(void* const* d_in, const int* in_sizes, int n_in,
                              void* d_out, int out_size, void* d_ws, size_t ws_size,
                              hipStream_t stream)
{
    const float* emb = (const float*)d_in[0];
    const float* Wq  = (const float*)d_in[1];
    const float* Wk  = (const float*)d_in[2];
    const float* Wv  = (const float*)d_in[3];
    float* out = (float*)d_out;

    unsigned short* Qp = (unsigned short*)d_ws;         // 2 MB packed Q frags
    unsigned short* Kp = Qp + (size_t)B_ * T_ * A_;     // 2 MB packed K frags
    unsigned short* Vp = Kp + (size_t)B_ * T_ * A_;     // 2 MB packed V frags
    unsigned short* Wp = Vp + (size_t)B_ * T_ * A_;     // 192 KB packed W frags

    prep_w<<<dim3(48), dim3(256), 0, stream>>>(Wq, Wk, Wv, Wp);
    qkv_proj_kernel<<<dim3(512), dim3(768), 0, stream>>>(emb, Wp, Qp, Kp, Vp);
    attn_kernel<<<dim3(256), dim3(512), 0, stream>>>(Qp, Kp, Vp, out);
}

// Round 21
// 44.270 us; speedup vs baseline: 1.3280x; 1.3280x over previous
//
#include <hip/hip_runtime.h>

#define B_ 4
#define T_ 4096
#define E_ 512
#define A_ 64
#define SQSCALE 0.1803368801111204f   // log2(e)/8 : folds softmax scale + exp->exp2

typedef __attribute__((ext_vector_type(8)))  short bf16x8;
typedef __attribute__((ext_vector_type(8)))  unsigned short ushort8;
typedef __attribute__((ext_vector_type(4)))  unsigned int   u32x4;
typedef __attribute__((ext_vector_type(4)))  float f32x4;
typedef __attribute__((ext_vector_type(16))) float f32x16;

__device__ __forceinline__ unsigned short f2bf(float x) {
    union { float f; unsigned int u; } v; v.f = x;
    unsigned int r = v.u + 0x7fffu + ((v.u >> 16) & 1u);
    return (unsigned short)(r >> 16);
}
__device__ __forceinline__ unsigned cvtpk(float a, float b) {
    unsigned r;
    asm("v_cvt_pk_bf16_f32 %0, %1, %2" : "=v"(r) : "v"(a), "v"(b));
    return r;
}
// v_permlane32_swap_b32 (distinct values only)
__device__ __forceinline__ void pls(unsigned &a, unsigned &b) {
    asm("v_permlane32_swap_b32 %0, %1" : "+v"(a), "+v"(b));
}

// ---- Kernel 0: W -> Wp, fragment-packed bf16 B-frags [nt 12][ks 16][lane 64]x8
__global__ __launch_bounds__(256) void prep_w(
    const float* __restrict__ Wq, const float* __restrict__ Wk,
    const float* __restrict__ Wv, unsigned short* __restrict__ Wp)
{
    const int e = blockIdx.x * 256 + threadIdx.x;   // 48*256 = 12288 entries
    const int nt = e >> 10;
    const int ks = (e >> 6) & 15;
    const int l  = e & 63;
    const int col = nt * 16 + (l & 15);
    const int kb  = ks * 32 + (l >> 4) * 8;
    const float* W = (col < 64) ? Wq : ((col < 128) ? Wk : Wv);
    const int cc = col & 63;
    const float sc = (col < 64) ? SQSCALE : 1.f;
    union { unsigned short s[8]; ushort8 v; } u;
    #pragma unroll
    for (int j = 0; j < 8; ++j) u.s[j] = f2bf(W[(kb + j) * 64 + cc] * sc);
    *(ushort8*)&Wp[(size_t)e * 8] = u.v;
}

// ---- Kernel 1: QKV projection via bf16 MFMA (R17 version, byte-identical) --
__global__ __launch_bounds__(768, 4) void qkv_proj_kernel(
    const float* __restrict__ emb, const unsigned short* __restrict__ Wp,
    unsigned short* __restrict__ Qp, unsigned short* __restrict__ Kp,
    unsigned short* __restrict__ Vp)
{
    __shared__ unsigned short at[32][536];   // 33.5 KB
    __shared__ unsigned short qt[32][72];    // 4.6 KB  [q][dim]
    __shared__ unsigned short kt[32][72];    // 4.6 KB  [key][dim]
    __shared__ unsigned short vt[64][40];    // 5.1 KB  [dim][key]
    const int tid = threadIdx.x;
    const long row0 = (long)blockIdx.x * 32;

    if (tid < 512) {
        const int r = tid >> 4, c16 = tid & 15;
        const float* __restrict__ src = emb + (row0 + r) * 512;
        #pragma unroll
        for (int j = 0; j < 4; ++j) {
            const int col = j * 128 + c16 * 8;
            const float4 x0 = *(const float4*)(src + col);
            const float4 x1 = *(const float4*)(src + col + 4);
            u32x4 p;
            p[0] = cvtpk(x0.x, x0.y); p[1] = cvtpk(x0.z, x0.w);
            p[2] = cvtpk(x1.x, x1.y); p[3] = cvtpk(x1.z, x1.w);
            *(u32x4*)&at[r][col] = p;
        }
    }
    __syncthreads();

    const int w = tid >> 6, lane = tid & 63;   // w = nt tile index, 0..11
    const int c = lane & 15, hi = lane >> 4;

    f32x4 acc[2];
    acc[0] = (f32x4){0.f, 0.f, 0.f, 0.f};
    acc[1] = (f32x4){0.f, 0.f, 0.f, 0.f};

    #pragma unroll
    for (int ks = 0; ks < 16; ++ks) {
        const bf16x8 bf_ = *(const bf16x8*)&Wp[((size_t)(w * 16 + ks) * 64 + lane) * 8];
        const bf16x8 a0 = *(const bf16x8*)&at[c][ks * 32 + hi * 8];
        const bf16x8 a1 = *(const bf16x8*)&at[16 + c][ks * 32 + hi * 8];
        acc[0] = __builtin_amdgcn_mfma_f32_16x16x32_bf16(a0, bf_, acc[0], 0, 0, 0);
        acc[1] = __builtin_amdgcn_mfma_f32_16x16x32_bf16(a1, bf_, acc[1], 0, 0, 0);
    }

    #pragma unroll
    for (int rr = 0; rr < 2; ++rr)
        #pragma unroll
        for (int r4 = 0; r4 < 4; ++r4) {
            const int rloc = rr * 16 + hi * 4 + r4;
            const unsigned short v = f2bf(acc[rr][r4]);
            if (w < 4)       qt[rloc][w * 16 + c] = v;
            else if (w < 8)  kt[rloc][(w - 4) * 16 + c] = v;
            else             vt[(w - 8) * 16 + c][rloc] = v;
        }
    __syncthreads();

    const int tloc = (int)(row0 & 4095);
    const long bb = row0 >> 12;
    const int ci  = tloc >> 6;
    const int f_  = (tloc >> 5) & 1;
    const int ks0 = (tloc >> 4) & 3;      // 0 or 2
    const int tt  = tloc >> 5;            // 32-q tile index 0..127
    if (tid < 256) {
        const int kk = tid >> 6, l = tid & 63;
        const ushort8 kval = *(const ushort8*)&kt[l & 31][kk * 16 + (l >> 5) * 8];
        *(ushort8*)&Kp[((((bb * 64 + ci) * 2 + f_) * 4 + kk) * 64 + l) * 8] = kval;
        const ushort8 qval = *(const ushort8*)&qt[l & 31][kk * 16 + (l >> 5) * 8];
        *(ushort8*)&Qp[(((bb * 128 + tt) * 4 + kk) * 64 + l) * 8] = qval;
    } else if (tid < 512) {
        const int e = tid - 256;
        const int ksl = e >> 7, ct = (e >> 6) & 1, l = e & 63;
        const ushort8 val = *(const ushort8*)&vt[ct * 32 + (l & 31)][ksl * 16 + (l >> 5) * 8];
        *(ushort8*)&Vp[((((bb * 64 + ci) * 4 + ks0 + ksl) * 2 + ct) * 64 + l) * 8] = val;
    }
}

// ---- Kernel 2: causal flash attention, two-tile ILP-2, register diet -------
// 256 blocks (1/CU), 8 waves. Tiles {127-pp, pp} advanced together (2 chains/
// wave). NO K double-buffer: kf is a step-local temp (dead after QK^T); V
// loaded after softmax (kf/vf lifetimes disjoint). amdgpu_waves_per_eu(2,2)
// sets the allocator's occupancy TARGET to 2 waves/SIMD -> 256-VGPR budget
// (R19/R20: launch_bounds min alone left the heuristic at 4 waves -> 128 cap
// -> 35 MB spill).
struct TS {
    const unsigned short* kptr;
    const unsigned short* vptr;
    bf16x8 qf[4];
    f32x16 acc[2];
    float m, l;
    int nc, qb, ci;
};

__device__ __forceinline__ void tile_init(TS& s, int t,
    const unsigned short* __restrict__ Qpb, const unsigned short* __restrict__ Kpb,
    const unsigned short* __restrict__ Vpb, int w, int lane)
{
    s.qb = t << 5;
    s.nc = ((s.qb + 31) >> 6) + 1;
    #pragma unroll
    for (int kk = 0; kk < 4; ++kk)
        s.qf[kk] = *(const bf16x8*)&Qpb[(((size_t)t * 4 + kk) * 64 + lane) * 8];
    #pragma unroll
    for (int ct = 0; ct < 2; ++ct)
        #pragma unroll
        for (int j = 0; j < 16; ++j) s.acc[ct][j] = 0.f;
    s.m = -1e30f; s.l = 0.f;
    s.kptr = Kpb + (size_t)w * 4096 + lane * 8;
    s.vptr = Vpb + (size_t)w * 4096 + lane * 8;
    s.ci = w;
}

__device__ __forceinline__ void tile_step(TS& s, int h)
{
    const int s0 = s.ci << 6;

    // K frags: step-local, dead after QK^T (register diet vs R19's dbuf)
    bf16x8 kf[2][4];
    #pragma unroll
    for (int f = 0; f < 2; ++f)
        #pragma unroll
        for (int kk = 0; kk < 4; ++kk)
            kf[f][kk] = *(const bf16x8*)&s.kptr[f * 2048 + kk * 512];

    // S^T = K Q^T : D[row=key][col=q]
    f32x16 sf[2];
    #pragma unroll
    for (int f = 0; f < 2; ++f)
        #pragma unroll
        for (int j = 0; j < 16; ++j) sf[f][j] = 0.f;
    __builtin_amdgcn_s_setprio(1);
    #pragma unroll
    for (int f = 0; f < 2; ++f)
        #pragma unroll
        for (int kk = 0; kk < 4; ++kk)
            sf[f] = __builtin_amdgcn_mfma_f32_32x32x16_bf16(kf[f][kk], s.qf[kk], sf[f], 0, 0, 0);
    __builtin_amdgcn_s_setprio(0);

    const int c = (int)(threadIdx.x & 31);
    // causal mask: key = s0 + 32f + (r&3) + 8*(r>>2) + 4h ; q = qb + c
    if (s0 + 63 > s.qb) {
        #pragma unroll
        for (int f = 0; f < 2; ++f)
            #pragma unroll
            for (int r = 0; r < 16; ++r) {
                const int key = s0 + f * 32 + ((r & 3) + 8 * (r >> 2)) + 4 * h;
                if (key > s.qb + c) sf[f][r] = -1e30f;
            }
    }

    // ---- online softmax (exp2 domain); 4-partial tree reductions ----
    float t0 = fmaxf(sf[0][0], sf[1][0]);
    float t1 = fmaxf(sf[0][1], sf[1][1]);
    float t2 = fmaxf(sf[0][2], sf[1][2]);
    float t3 = fmaxf(sf[0][3], sf[1][3]);
    #pragma unroll
    for (int r = 4; r < 16; r += 4) {
        t0 = fmaxf(t0, fmaxf(sf[0][r],     sf[1][r]));
        t1 = fmaxf(t1, fmaxf(sf[0][r + 1], sf[1][r + 1]));
        t2 = fmaxf(t2, fmaxf(sf[0][r + 2], sf[1][r + 2]));
        t3 = fmaxf(t3, fmaxf(sf[0][r + 3], sf[1][r + 3]));
    }
    float pm = fmaxf(fmaxf(t0, t1), fmaxf(t2, t3));
    pm = fmaxf(pm, __shfl_xor(pm, 32));

    float mn = s.m;
    if (__any(pm > s.m)) {             // exact skip: if no column grew, sc == 1
        mn = fmaxf(s.m, pm);
        const float sc = exp2f(s.m - mn);   // per-lane scalar (q = c)
        s.m = mn;
        s.l *= sc;
        #pragma unroll
        for (int ct = 0; ct < 2; ++ct)
            #pragma unroll
            for (int r = 0; r < 16; ++r) s.acc[ct][r] *= sc;
    }

    float s0a = 0.f, s1a = 0.f, s2a = 0.f, s3a = 0.f;
    #pragma unroll
    for (int f = 0; f < 2; ++f)
        #pragma unroll
        for (int r = 0; r < 16; r += 4) {
            float p0 = exp2f(sf[f][r] - mn);
            float p1 = exp2f(sf[f][r + 1] - mn);
            float p2 = exp2f(sf[f][r + 2] - mn);
            float p3 = exp2f(sf[f][r + 3] - mn);
            sf[f][r] = p0; sf[f][r + 1] = p1; sf[f][r + 2] = p2; sf[f][r + 3] = p3;
            s0a += p0; s1a += p1; s2a += p2; s3a += p3;
        }
    float rs = (s0a + s1a) + (s2a + s3a);
    rs += __shfl_xor(rs, 32);
    s.l += rs;

    // V frags loaded AFTER softmax: vf/kf lifetimes disjoint (register diet)
    bf16x8 vf[4][2];
    #pragma unroll
    for (int ks = 0; ks < 4; ++ks)
        #pragma unroll
        for (int ct = 0; ct < 2; ++ct)
            vf[ks][ct] = *(const bf16x8*)&s.vptr[ks * 1024 + ct * 512];

    // ---- P -> bf16 frags via cvt_pk + permlane32_swap; O^T += V^T P ----
    #pragma unroll
    for (int f = 0; f < 2; ++f) {
        unsigned w01 = cvtpk(sf[f][0], sf[f][1]);
        unsigned w23 = cvtpk(sf[f][2], sf[f][3]);
        unsigned w45 = cvtpk(sf[f][4], sf[f][5]);
        unsigned w67 = cvtpk(sf[f][6], sf[f][7]);
        pls(w01, w45); pls(w23, w67);
        union { unsigned uu[4]; bf16x8 v; } pa0, pa1;
        pa0.uu[0] = w01; pa0.uu[1] = w23; pa0.uu[2] = w45; pa0.uu[3] = w67;
        unsigned x01 = cvtpk(sf[f][8],  sf[f][9]);
        unsigned x23 = cvtpk(sf[f][10], sf[f][11]);
        unsigned x45 = cvtpk(sf[f][12], sf[f][13]);
        unsigned x67 = cvtpk(sf[f][14], sf[f][15]);
        pls(x01, x45); pls(x23, x67);
        pa1.uu[0] = x01; pa1.uu[1] = x23; pa1.uu[2] = x45; pa1.uu[3] = x67;
        __builtin_amdgcn_s_setprio(1);
        #pragma unroll
        for (int ct = 0; ct < 2; ++ct) {
            s.acc[ct] = __builtin_amdgcn_mfma_f32_32x32x16_bf16(vf[2 * f][ct],     pa0.v, s.acc[ct], 0, 0, 0);
            s.acc[ct] = __builtin_amdgcn_mfma_f32_32x32x16_bf16(vf[2 * f + 1][ct], pa1.v, s.acc[ct], 0, 0, 0);
        }
        __builtin_amdgcn_s_setprio(0);
    }

    s.kptr += 32768;
    s.vptr += 32768;
    s.ci += 8;
}

__global__ __launch_bounds__(512)
__attribute__((amdgpu_waves_per_eu(2, 2)))
void attn_kernel(
    const unsigned short* __restrict__ Qp, const unsigned short* __restrict__ Kp,
    const unsigned short* __restrict__ Vp, float* __restrict__ out)
{
    __shared__ float accbuf[8][32][68];   // 69.6 KB, [q][d] pad 68
    __shared__ float mbuf[8][32], lbuf[8][32];

    const int tid = threadIdx.x, w = tid >> 6, lane = tid & 63;
    const int c = lane & 31, h = lane >> 5;
    const int b = blockIdx.x & 3;
    const int pp = blockIdx.x >> 2;       // 0..63

    const unsigned short* __restrict__ Qpb = Qp + (size_t)b * 128 * 4 * 512;
    const unsigned short* __restrict__ Kpb = Kp + (size_t)b * 64 * 8 * 512;
    const unsigned short* __restrict__ Vpb = Vp + (size_t)b * 64 * 8 * 512;

    TS A, Bt;
    tile_init(A,  127 - pp, Qpb, Kpb, Vpb, w, lane);
    tile_init(Bt, pp,       Qpb, Kpb, Vpb, w, lane);
    const int itA = (A.nc  > w) ? ((A.nc  - w + 7) >> 3) : 0;
    const int itB = (Bt.nc > w) ? ((Bt.nc - w + 7) >> 3) : 0;

    for (int i = 0; i < itA; ++i) {
        tile_step(A, h);
        if (i < itB) tile_step(Bt, h);   // wave-uniform predicate; itA >= itB
    }

    // ---- merge + store, tile A then tile B (accbuf reused) ----
    #pragma unroll
    for (int which = 0; which < 2; ++which) {
        if (which == 0) {
            if (h == 0) { mbuf[w][c] = A.m; lbuf[w][c] = A.l; }
            #pragma unroll
            for (int ct = 0; ct < 2; ++ct)
                #pragma unroll
                for (int g = 0; g < 4; ++g)
                    *(float4*)&accbuf[w][c][ct * 32 + g * 8 + 4 * h] =
                        make_float4(A.acc[ct][4 * g], A.acc[ct][4 * g + 1],
                                    A.acc[ct][4 * g + 2], A.acc[ct][4 * g + 3]);
        } else {
            if (h == 0) { mbuf[w][c] = Bt.m; lbuf[w][c] = Bt.l; }
            #pragma unroll
            for (int ct = 0; ct < 2; ++ct)
                #pragma unroll
                for (int g = 0; g < 4; ++g)
                    *(float4*)&accbuf[w][c][ct * 32 + g * 8 + 4 * h] =
                        make_float4(Bt.acc[ct][4 * g], Bt.acc[ct][4 * g + 1],
                                    Bt.acc[ct][4 * g + 2], Bt.acc[ct][4 * g + 3]);
        }
        __syncthreads();
        const int qb = which ? (pp << 5) : ((127 - pp) << 5);
        #pragma unroll
        for (int i = 0; i < 4; ++i) {
            const int e = tid + i * 512;
            const int q = e >> 6, d = e & 63;
            float ms = mbuf[0][q];
            #pragma unroll
            for (int wv = 1; wv < 8; ++wv) ms = fmaxf(ms, mbuf[wv][q]);
            float ls = 0.f, os = 0.f;
            #pragma unroll
            for (int wv = 0; wv < 8; ++wv) {
                const float e_ = exp2f(mbuf[wv][q] - ms);
                ls += lbuf[wv][q] * e_;
                os += accbuf[wv][q][d] * e_;
            }
            out[((long)b * T_ + qb + q) * 64 + d] = os / ls;
        }
        __syncthreads();   // protect accbuf/mbuf/lbuf reuse
    }
}

extern "C" void kernel_launch(void* const* d_in, const int* in_sizes, int n_in,
                              void* d_out, int out_size, void* d_ws, size_t ws_size,
                              hipStream_t stream)
{
    const float* emb = (const float*)d_in[0];
    const float* Wq  = (const float*)d_in[1];
    const float* Wk  = (const float*)d_in[2];
    const float* Wv  = (const float*)d_in[3];
    float* out = (float*)d_out;

    unsigned short* Qp = (unsigned short*)d_ws;         // 2 MB packed Q frags
    unsigned short* Kp = Qp + (size_t)B_ * T_ * A_;     // 2 MB packed K frags
    unsigned short* Vp = Kp + (size_t)B_ * T_ * A_;     // 2 MB packed V frags
    unsigned short* Wp = Vp + (size_t)B_ * T_ * A_;     // 192 KB packed W frags

    prep_w<<<dim3(48), dim3(256), 0, stream>>>(Wq, Wk, Wv, Wp);
    qkv_proj_kernel<<<dim3(512), dim3(768), 0, stream>>>(emb, Wp, Qp, Kp, Vp);
    attn_kernel<<<dim3(256), dim3(512), 0, stream>>>(Qp, Kp, Vp, out);
}

// Round 22
// 43.567 us; speedup vs baseline: 1.3494x; 1.0161x over previous
//
#include <hip/hip_runtime.h>

#define B_ 4
#define T_ 4096
#define E_ 512
#define A_ 64
#define SQSCALE 0.1803368801111204f   // log2(e)/8 : folds softmax scale + exp->exp2

typedef __attribute__((ext_vector_type(8)))  short bf16x8;
typedef __attribute__((ext_vector_type(8)))  unsigned short ushort8;
typedef __attribute__((ext_vector_type(4)))  unsigned int   u32x4;
typedef __attribute__((ext_vector_type(4)))  float f32x4;
typedef __attribute__((ext_vector_type(16))) float f32x16;

__device__ __forceinline__ unsigned short f2bf(float x) {
    union { float f; unsigned int u; } v; v.f = x;
    unsigned int r = v.u + 0x7fffu + ((v.u >> 16) & 1u);
    return (unsigned short)(r >> 16);
}
__device__ __forceinline__ unsigned cvtpk(float a, float b) {
    unsigned r;
    asm("v_cvt_pk_bf16_f32 %0, %1, %2" : "=v"(r) : "v"(a), "v"(b));
    return r;
}
// v_permlane32_swap_b32 (distinct values only)
__device__ __forceinline__ void pls(unsigned &a, unsigned &b) {
    asm("v_permlane32_swap_b32 %0, %1" : "+v"(a), "+v"(b));
}

// ---- Kernel 0: W -> Wp, fragment-packed bf16 B-frags [nt 12][ks 16][lane 64]x8
__global__ __launch_bounds__(256) void prep_w(
    const float* __restrict__ Wq, const float* __restrict__ Wk,
    const float* __restrict__ Wv, unsigned short* __restrict__ Wp)
{
    const int e = blockIdx.x * 256 + threadIdx.x;   // 48*256 = 12288 entries
    const int nt = e >> 10;
    const int ks = (e >> 6) & 15;
    const int l  = e & 63;
    const int col = nt * 16 + (l & 15);
    const int kb  = ks * 32 + (l >> 4) * 8;
    const float* W = (col < 64) ? Wq : ((col < 128) ? Wk : Wv);
    const int cc = col & 63;
    const float sc = (col < 64) ? SQSCALE : 1.f;
    union { unsigned short s[8]; ushort8 v; } u;
    #pragma unroll
    for (int j = 0; j < 8; ++j) u.s[j] = f2bf(W[(kb + j) * 64 + cc] * sc);
    *(ushort8*)&Wp[(size_t)e * 8] = u.v;
}

// ---- Kernel 1: QKV projection via bf16 MFMA (R17 version, byte-identical) --
__global__ __launch_bounds__(768, 4) void qkv_proj_kernel(
    const float* __restrict__ emb, const unsigned short* __restrict__ Wp,
    unsigned short* __restrict__ Qp, unsigned short* __restrict__ Kp,
    unsigned short* __restrict__ Vp)
{
    __shared__ unsigned short at[32][536];   // 33.5 KB
    __shared__ unsigned short qt[32][72];    // 4.6 KB  [q][dim]
    __shared__ unsigned short kt[32][72];    // 4.6 KB  [key][dim]
    __shared__ unsigned short vt[64][40];    // 5.1 KB  [dim][key]
    const int tid = threadIdx.x;
    const long row0 = (long)blockIdx.x * 32;

    if (tid < 512) {
        const int r = tid >> 4, c16 = tid & 15;
        const float* __restrict__ src = emb + (row0 + r) * 512;
        #pragma unroll
        for (int j = 0; j < 4; ++j) {
            const int col = j * 128 + c16 * 8;
            const float4 x0 = *(const float4*)(src + col);
            const float4 x1 = *(const float4*)(src + col + 4);
            u32x4 p;
            p[0] = cvtpk(x0.x, x0.y); p[1] = cvtpk(x0.z, x0.w);
            p[2] = cvtpk(x1.x, x1.y); p[3] = cvtpk(x1.z, x1.w);
            *(u32x4*)&at[r][col] = p;
        }
    }
    __syncthreads();

    const int w = tid >> 6, lane = tid & 63;   // w = nt tile index, 0..11
    const int c = lane & 15, hi = lane >> 4;

    f32x4 acc[2];
    acc[0] = (f32x4){0.f, 0.f, 0.f, 0.f};
    acc[1] = (f32x4){0.f, 0.f, 0.f, 0.f};

    #pragma unroll
    for (int ks = 0; ks < 16; ++ks) {
        const bf16x8 bf_ = *(const bf16x8*)&Wp[((size_t)(w * 16 + ks) * 64 + lane) * 8];
        const bf16x8 a0 = *(const bf16x8*)&at[c][ks * 32 + hi * 8];
        const bf16x8 a1 = *(const bf16x8*)&at[16 + c][ks * 32 + hi * 8];
        acc[0] = __builtin_amdgcn_mfma_f32_16x16x32_bf16(a0, bf_, acc[0], 0, 0, 0);
        acc[1] = __builtin_amdgcn_mfma_f32_16x16x32_bf16(a1, bf_, acc[1], 0, 0, 0);
    }

    #pragma unroll
    for (int rr = 0; rr < 2; ++rr)
        #pragma unroll
        for (int r4 = 0; r4 < 4; ++r4) {
            const int rloc = rr * 16 + hi * 4 + r4;
            const unsigned short v = f2bf(acc[rr][r4]);
            if (w < 4)       qt[rloc][w * 16 + c] = v;
            else if (w < 8)  kt[rloc][(w - 4) * 16 + c] = v;
            else             vt[(w - 8) * 16 + c][rloc] = v;
        }
    __syncthreads();

    const int tloc = (int)(row0 & 4095);
    const long bb = row0 >> 12;
    const int ci  = tloc >> 6;
    const int f_  = (tloc >> 5) & 1;
    const int ks0 = (tloc >> 4) & 3;      // 0 or 2
    const int tt  = tloc >> 5;            // 32-q tile index 0..127
    if (tid < 256) {
        const int kk = tid >> 6, l = tid & 63;
        const ushort8 kval = *(const ushort8*)&kt[l & 31][kk * 16 + (l >> 5) * 8];
        *(ushort8*)&Kp[((((bb * 64 + ci) * 2 + f_) * 4 + kk) * 64 + l) * 8] = kval;
        const ushort8 qval = *(const ushort8*)&qt[l & 31][kk * 16 + (l >> 5) * 8];
        *(ushort8*)&Qp[(((bb * 128 + tt) * 4 + kk) * 64 + l) * 8] = qval;
    } else if (tid < 512) {
        const int e = tid - 256;
        const int ksl = e >> 7, ct = (e >> 6) & 1, l = e & 63;
        const ushort8 val = *(const ushort8*)&vt[ct * 32 + (l & 31)][ksl * 16 + (l >> 5) * 8];
        *(ushort8*)&Vp[((((bb * 64 + ci) * 4 + ks0 + ksl) * 2 + ct) * 64 + l) * 8] = val;
    }
}

// ---- Kernel 2: causal flash attention, ILP-2 with SHARED K/V loads ---------
// 256 blocks (1/CU), 8 waves. Tiles A={127-pp}, B={pp} walk IDENTICAL chunk
// indices (both start at ci=w, step +8) -> one kf/vf load set per iteration
// feeds BOTH tiles' QK^T and PV (R21 loaded everything twice). Both tiles'
// compute sits between consecutive load sets -> mutual latency hiding.
struct TS {
    bf16x8 qf[4];
    f32x16 acc[2];
    float m, l;
    int qb;
};

__device__ __forceinline__ void tile_init(TS& s, int t,
    const unsigned short* __restrict__ Qpb, int lane)
{
    s.qb = t << 5;
    #pragma unroll
    for (int kk = 0; kk < 4; ++kk)
        s.qf[kk] = *(const bf16x8*)&Qpb[(((size_t)t * 4 + kk) * 64 + lane) * 8];
    #pragma unroll
    for (int ct = 0; ct < 2; ++ct)
        #pragma unroll
        for (int j = 0; j < 16; ++j) s.acc[ct][j] = 0.f;
    s.m = -1e30f; s.l = 0.f;
}

__device__ __forceinline__ void tile_compute(TS& s, const bf16x8 kf[2][4],
    const bf16x8 vf[4][2], int s0, int h, int c)
{
    // S^T = K Q^T : D[row=key][col=q]
    f32x16 sf[2];
    #pragma unroll
    for (int f = 0; f < 2; ++f)
        #pragma unroll
        for (int j = 0; j < 16; ++j) sf[f][j] = 0.f;
    __builtin_amdgcn_s_setprio(1);
    #pragma unroll
    for (int f = 0; f < 2; ++f)
        #pragma unroll
        for (int kk = 0; kk < 4; ++kk)
            sf[f] = __builtin_amdgcn_mfma_f32_32x32x16_bf16(kf[f][kk], s.qf[kk], sf[f], 0, 0, 0);
    __builtin_amdgcn_s_setprio(0);

    // causal mask: key = s0 + 32f + (r&3) + 8*(r>>2) + 4h ; q = qb + c
    if (s0 + 63 > s.qb) {
        #pragma unroll
        for (int f = 0; f < 2; ++f)
            #pragma unroll
            for (int r = 0; r < 16; ++r) {
                const int key = s0 + f * 32 + ((r & 3) + 8 * (r >> 2)) + 4 * h;
                if (key > s.qb + c) sf[f][r] = -1e30f;
            }
    }

    // ---- online softmax (exp2 domain); 4-partial tree reductions ----
    float t0 = fmaxf(sf[0][0], sf[1][0]);
    float t1 = fmaxf(sf[0][1], sf[1][1]);
    float t2 = fmaxf(sf[0][2], sf[1][2]);
    float t3 = fmaxf(sf[0][3], sf[1][3]);
    #pragma unroll
    for (int r = 4; r < 16; r += 4) {
        t0 = fmaxf(t0, fmaxf(sf[0][r],     sf[1][r]));
        t1 = fmaxf(t1, fmaxf(sf[0][r + 1], sf[1][r + 1]));
        t2 = fmaxf(t2, fmaxf(sf[0][r + 2], sf[1][r + 2]));
        t3 = fmaxf(t3, fmaxf(sf[0][r + 3], sf[1][r + 3]));
    }
    float pm = fmaxf(fmaxf(t0, t1), fmaxf(t2, t3));
    pm = fmaxf(pm, __shfl_xor(pm, 32));

    float mn = s.m;
    if (__any(pm > s.m)) {             // exact skip: if no column grew, sc == 1
        mn = fmaxf(s.m, pm);
        const float sc = exp2f(s.m - mn);   // per-lane scalar (q = c)
        s.m = mn;
        s.l *= sc;
        #pragma unroll
        for (int ct = 0; ct < 2; ++ct)
            #pragma unroll
            for (int r = 0; r < 16; ++r) s.acc[ct][r] *= sc;
    }

    float s0a = 0.f, s1a = 0.f, s2a = 0.f, s3a = 0.f;
    #pragma unroll
    for (int f = 0; f < 2; ++f)
        #pragma unroll
        for (int r = 0; r < 16; r += 4) {
            float p0 = exp2f(sf[f][r] - mn);
            float p1 = exp2f(sf[f][r + 1] - mn);
            float p2 = exp2f(sf[f][r + 2] - mn);
            float p3 = exp2f(sf[f][r + 3] - mn);
            sf[f][r] = p0; sf[f][r + 1] = p1; sf[f][r + 2] = p2; sf[f][r + 3] = p3;
            s0a += p0; s1a += p1; s2a += p2; s3a += p3;
        }
    float rs = (s0a + s1a) + (s2a + s3a);
    rs += __shfl_xor(rs, 32);
    s.l += rs;

    // ---- P -> bf16 frags via cvt_pk + permlane32_swap; O^T += V^T P ----
    #pragma unroll
    for (int f = 0; f < 2; ++f) {
        unsigned w01 = cvtpk(sf[f][0], sf[f][1]);
        unsigned w23 = cvtpk(sf[f][2], sf[f][3]);
        unsigned w45 = cvtpk(sf[f][4], sf[f][5]);
        unsigned w67 = cvtpk(sf[f][6], sf[f][7]);
        pls(w01, w45); pls(w23, w67);
        union { unsigned uu[4]; bf16x8 v; } pa0, pa1;
        pa0.uu[0] = w01; pa0.uu[1] = w23; pa0.uu[2] = w45; pa0.uu[3] = w67;
        unsigned x01 = cvtpk(sf[f][8],  sf[f][9]);
        unsigned x23 = cvtpk(sf[f][10], sf[f][11]);
        unsigned x45 = cvtpk(sf[f][12], sf[f][13]);
        unsigned x67 = cvtpk(sf[f][14], sf[f][15]);
        pls(x01, x45); pls(x23, x67);
        pa1.uu[0] = x01; pa1.uu[1] = x23; pa1.uu[2] = x45; pa1.uu[3] = x67;
        __builtin_amdgcn_s_setprio(1);
        #pragma unroll
        for (int ct = 0; ct < 2; ++ct) {
            s.acc[ct] = __builtin_amdgcn_mfma_f32_32x32x16_bf16(vf[2 * f][ct],     pa0.v, s.acc[ct], 0, 0, 0);
            s.acc[ct] = __builtin_amdgcn_mfma_f32_32x32x16_bf16(vf[2 * f + 1][ct], pa1.v, s.acc[ct], 0, 0, 0);
        }
        __builtin_amdgcn_s_setprio(0);
    }
}

__global__ __launch_bounds__(512)
__attribute__((amdgpu_waves_per_eu(2, 2)))
void attn_kernel(
    const unsigned short* __restrict__ Qp, const unsigned short* __restrict__ Kp,
    const unsigned short* __restrict__ Vp, float* __restrict__ out)
{
    __shared__ float accbuf[8][32][68];   // 69.6 KB, [q][d] pad 68
    __shared__ float mbuf[8][32], lbuf[8][32];

    const int tid = threadIdx.x, w = tid >> 6, lane = tid & 63;
    const int c = lane & 31, h = lane >> 5;
    const int b = blockIdx.x & 3;
    const int pp = blockIdx.x >> 2;       // 0..63

    const unsigned short* __restrict__ Qpb = Qp + (size_t)b * 128 * 4 * 512;
    const unsigned short* __restrict__ Kpb = Kp + (size_t)b * 64 * 8 * 512;
    const unsigned short* __restrict__ Vpb = Vp + (size_t)b * 64 * 8 * 512;

    TS A, Bt;
    tile_init(A,  127 - pp, Qpb, lane);
    tile_init(Bt, pp,       Qpb, lane);
    const int ncA = ((A.qb  + 31) >> 6) + 1;
    const int ncB = ((Bt.qb + 31) >> 6) + 1;
    const int itA = (ncA > w) ? ((ncA - w + 7) >> 3) : 0;
    const int itB = (ncB > w) ? ((ncB - w + 7) >> 3) : 0;

    const unsigned short* kptr = Kpb + (size_t)w * 4096 + lane * 8;
    const unsigned short* vptr = Vpb + (size_t)w * 4096 + lane * 8;

    for (int i = 0; i < itA; ++i) {
        const int s0 = (w + i * 8) << 6;

        // shared K/V fragment loads: feed BOTH tiles this iteration
        bf16x8 kf[2][4];
        #pragma unroll
        for (int f = 0; f < 2; ++f)
            #pragma unroll
            for (int kk = 0; kk < 4; ++kk)
                kf[f][kk] = *(const bf16x8*)&kptr[f * 2048 + kk * 512];
        bf16x8 vf[4][2];
        #pragma unroll
        for (int ks = 0; ks < 4; ++ks)
            #pragma unroll
            for (int ct = 0; ct < 2; ++ct)
                vf[ks][ct] = *(const bf16x8*)&vptr[ks * 1024 + ct * 512];

        tile_compute(A, kf, vf, s0, h, c);
        if (i < itB) tile_compute(Bt, kf, vf, s0, h, c);   // wave-uniform; itA >= itB

        kptr += 32768;
        vptr += 32768;
    }

    // ---- merge + store, tile A then tile B (accbuf reused) ----
    #pragma unroll
    for (int which = 0; which < 2; ++which) {
        if (which == 0) {
            if (h == 0) { mbuf[w][c] = A.m; lbuf[w][c] = A.l; }
            #pragma unroll
            for (int ct = 0; ct < 2; ++ct)
                #pragma unroll
                for (int g = 0; g < 4; ++g)
                    *(float4*)&accbuf[w][c][ct * 32 + g * 8 + 4 * h] =
                        make_float4(A.acc[ct][4 * g], A.acc[ct][4 * g + 1],
                                    A.acc[ct][4 * g + 2], A.acc[ct][4 * g + 3]);
        } else {
            if (h == 0) { mbuf[w][c] = Bt.m; lbuf[w][c] = Bt.l; }
            #pragma unroll
            for (int ct = 0; ct < 2; ++ct)
                #pragma unroll
                for (int g = 0; g < 4; ++g)
                    *(float4*)&accbuf[w][c][ct * 32 + g * 8 + 4 * h] =
                        make_float4(Bt.acc[ct][4 * g], Bt.acc[ct][4 * g + 1],
                                    Bt.acc[ct][4 * g + 2], Bt.acc[ct][4 * g + 3]);
        }
        __syncthreads();
        const int qb = which ? (pp << 5) : ((127 - pp) << 5);
        #pragma unroll
        for (int i = 0; i < 4; ++i) {
            const int e = tid + i * 512;
            const int q = e >> 6, d = e & 63;
            float ms = mbuf[0][q];
            #pragma unroll
            for (int wv = 1; wv < 8; ++wv) ms = fmaxf(ms, mbuf[wv][q]);
            float ls = 0.f, os = 0.f;
            #pragma unroll
            for (int wv = 0; wv < 8; ++wv) {
                const float e_ = exp2f(mbuf[wv][q] - ms);
                ls += lbuf[wv][q] * e_;
                os += accbuf[wv][q][d] * e_;
            }
            out[((long)b * T_ + qb + q) * 64 + d] = os / ls;
        }
        __syncthreads();   // protect accbuf/mbuf/lbuf reuse
    }
}

extern "C" void kernel_launch(void* const* d_in, const int* in_sizes, int n_in,
                              void* d_out, int out_size, void* d_ws, size_t ws_size,
                              hipStream_t stream)
{
    const float* emb = (const float*)d_in[0];
    const float* Wq  = (const float*)d_in[1];
    const float* Wk  = (const float*)d_in[2];
    const float* Wv  = (const float*)d_in[3];
    float* out = (float*)d_out;

    unsigned short* Qp = (unsigned short*)d_ws;         // 2 MB packed Q frags
    unsigned short* Kp = Qp + (size_t)B_ * T_ * A_;     // 2 MB packed K frags
    unsigned short* Vp = Kp + (size_t)B_ * T_ * A_;     // 2 MB packed V frags
    unsigned short* Wp = Vp + (size_t)B_ * T_ * A_;     // 192 KB packed W frags

    prep_w<<<dim3(48), dim3(256), 0, stream>>>(Wq, Wk, Wv, Wp);
    qkv_proj_kernel<<<dim3(512), dim3(768), 0, stream>>>(emb, Wp, Qp, Kp, Vp);
    attn_kernel<<<dim3(256), dim3(512), 0, stream>>>(Qp, Kp, Vp, out);
}